// Round 10
// baseline (130.803 us; speedup 1.0000x reference)
//
#include <hip/hip_runtime.h>

// VoxelQueryAndGrouping — MI355X (gfx950), round 10
// = round-5 kernel (PASSED, 53.4us; QPW=2, ds_permute slot scatter) made
//   PERSISTENT: 8192 grid-stride waves, each looping over ~3-4 query-pairs
//   with cross-iteration software pipelining — the next pair's descriptors
//   and v2p gathers are issued before the current pair's ballot/store phase,
//   hiding the longest-latency stage under the current iteration's tail.
// All output-producing code is byte-identical to round 5. Single kernel.

constexpr int ZG = 21;
constexpr int YG = 400;
constexpr int XG = 352;
constexpr int NS = 16;   // NSAMPLE
constexpr int CF = 32;   // feature channels
constexpr float R2 = 64.0f; // RADIUS^2

typedef float v4f __attribute__((ext_vector_type(4)));

struct PairDesc {
    int4  qc0, qc1;
    float qx0, qy0, qz0, qx1, qy1, qz1;
    int   boff0, boff1;
    bool  has1;
};

__global__ __launch_bounds__(256) void vqg_kernel(
    const int*   __restrict__ new_coords,     // (M,4) [b,z,y,x]
    const float* __restrict__ xyz,            // (N,3)
    const int*   __restrict__ xyz_batch_cnt,  // (B,)
    const float* __restrict__ new_xyz,        // (M,3)
    const float* __restrict__ features,       // (N,CF)
    const int*   __restrict__ v2p,            // (B,ZG,YG,XG)
    float* __restrict__ out_feat,             // (M,CF,NS)
    float* __restrict__ out_xyz,              // (M,3,NS)
    float* __restrict__ out_empty,            // (M,)
    int M, int nwaves)
{
    const int lane = threadIdx.x & 63;
    const int w    = (blockIdx.x * 256 + threadIdx.x) >> 6;  // global wave id
    const int npairs = (M + 1) / 2;
    int slot = w;
    if (slot >= npairs) return;               // wave-uniform

    // ---- neighbor decode (loop-invariant; reference order dz slow, dx fast) ----
    const int n1 = 64 + lane;
    const int dz0 = lane / 25 - 2, dy0 = (lane / 5) % 5 - 2, dx0 = lane % 5 - 2;
    const int dz1 = n1 / 25 - 2,   dy1 = (n1 / 5) % 5 - 2,   dx1 = n1 % 5 - 2;
    const bool in1 = (n1 < 125);
    const unsigned long long below = (1ull << lane) - 1ull;
    const int junk = (16 + (lane & 31)) << 2;

    // ---- descriptor + v2p gather issue for a pair (prefetch stage) ----
    auto load_desc = [&](int s, PairDesc& d) {
        const int m0 = s * 2, m1 = m0 + 1;
        d.has1 = (m1 < M);
        d.qc0 = *reinterpret_cast<const int4*>(new_coords + (size_t)m0 * 4);
        d.qc1 = d.has1 ? *reinterpret_cast<const int4*>(new_coords + (size_t)m1 * 4) : d.qc0;
        d.qx0 = new_xyz[m0 * 3 + 0]; d.qy0 = new_xyz[m0 * 3 + 1]; d.qz0 = new_xyz[m0 * 3 + 2];
        d.qx1 = d.has1 ? new_xyz[m1 * 3 + 0] : 0.f;
        d.qy1 = d.has1 ? new_xyz[m1 * 3 + 1] : 0.f;
        d.qz1 = d.has1 ? new_xyz[m1 * 3 + 2] : 0.f;
        int b0 = 0, b1 = 0;
        for (int i = 0; i < d.qc0.x; ++i) b0 += xyz_batch_cnt[i];
        for (int i = 0; i < d.qc1.x; ++i) b1 += xyz_batch_cnt[i];
        d.boff0 = b0; d.boff1 = b1;
    };
    auto load_v2p = [&](const PairDesc& d, int& pa0, int& pa1, int& pb0, int& pb1) {
        const int* __restrict__ gb0 = v2p + (size_t)d.qc0.x * (ZG * YG * XG);
        const int* __restrict__ gb1 = v2p + (size_t)d.qc1.x * (ZG * YG * XG);
        pa0 = -1; pa1 = -1; pb0 = -1; pb1 = -1;
        {
            const int z = d.qc0.y + dz0, y = d.qc0.z + dy0, x = d.qc0.w + dx0;
            if ((unsigned)z < (unsigned)ZG && (unsigned)y < (unsigned)YG && (unsigned)x < (unsigned)XG)
                pa0 = gb0[((size_t)z * YG + y) * XG + x];
        }
        {
            const int z = d.qc0.y + dz1, y = d.qc0.z + dy1, x = d.qc0.w + dx1;
            if (in1 && (unsigned)z < (unsigned)ZG && (unsigned)y < (unsigned)YG && (unsigned)x < (unsigned)XG)
                pa1 = gb0[((size_t)z * YG + y) * XG + x];
        }
        if (d.has1) {
            const int z = d.qc1.y + dz0, y = d.qc1.z + dy0, x = d.qc1.w + dx0;
            if ((unsigned)z < (unsigned)ZG && (unsigned)y < (unsigned)YG && (unsigned)x < (unsigned)XG)
                pb0 = gb1[((size_t)z * YG + y) * XG + x];
        }
        if (d.has1) {
            const int z = d.qc1.y + dz1, y = d.qc1.z + dy1, x = d.qc1.w + dx1;
            if (in1 && (unsigned)z < (unsigned)ZG && (unsigned)y < (unsigned)YG && (unsigned)x < (unsigned)XG)
                pb1 = gb1[((size_t)z * YG + y) * XG + x];
        }
    };

    // ---- prologue: prefetch first pair ----
    PairDesc cur;
    int pa0, pa1, pb0, pb1;
    load_desc(slot, cur);
    load_v2p(cur, pa0, pa1, pb0, pb1);

    for (;;) {
        const int m0 = slot * 2, m1 = m0 + 1;
        const bool has1 = cur.has1;

        // ---- candidate-point gathers for current (r5 pattern: 3 dwords) ----
        float a0x = 0, a0y = 0, a0z = 0, a1x = 0, a1y = 0, a1z = 0;
        float b0x = 0, b0y = 0, b0z = 0, b1x = 0, b1y = 0, b1z = 0;
        if (pa0 >= 0) { const float* p = xyz + (size_t)pa0 * 3; a0x = p[0]; a0y = p[1]; a0z = p[2]; }
        if (pa1 >= 0) { const float* p = xyz + (size_t)pa1 * 3; a1x = p[0]; a1y = p[1]; a1z = p[2]; }
        if (pb0 >= 0) { const float* p = xyz + (size_t)pb0 * 3; b0x = p[0]; b0y = p[1]; b0z = p[2]; }
        if (pb1 >= 0) { const float* p = xyz + (size_t)pb1 * 3; b1x = p[0]; b1y = p[1]; b1z = p[2]; }

        // ---- PREFETCH next pair (desc + v2p) while xyz loads are in flight ----
        const int nslot = slot + nwaves;
        const bool hasnext = (nslot < npairs);
        PairDesc nxt;
        int na0 = -1, na1 = -1, nb0 = -1, nb1 = -1;
        if (hasnext) {
            load_desc(nslot, nxt);
            load_v2p(nxt, na0, na1, nb0, nb1);
        }

        // ---- distances (exact reference association, no FMA) ----
        bool va0 = false, va1 = false, vb0 = false, vb1 = false;
        if (pa0 >= 0) {
            const float dx = a0x - cur.qx0, dy = a0y - cur.qy0, dz = a0z - cur.qz0;
            va0 = __fadd_rn(__fadd_rn(__fmul_rn(dx, dx), __fmul_rn(dy, dy)), __fmul_rn(dz, dz)) < R2;
        }
        if (pa1 >= 0) {
            const float dx = a1x - cur.qx0, dy = a1y - cur.qy0, dz = a1z - cur.qz0;
            va1 = __fadd_rn(__fadd_rn(__fmul_rn(dx, dx), __fmul_rn(dy, dy)), __fmul_rn(dz, dz)) < R2;
        }
        if (pb0 >= 0) {
            const float dx = b0x - cur.qx1, dy = b0y - cur.qy1, dz = b0z - cur.qz1;
            vb0 = __fadd_rn(__fadd_rn(__fmul_rn(dx, dx), __fmul_rn(dy, dy)), __fmul_rn(dz, dz)) < R2;
        }
        if (pb1 >= 0) {
            const float dx = b1x - cur.qx1, dy = b1y - cur.qy1, dz = b1z - cur.qz1;
            vb1 = __fadd_rn(__fadd_rn(__fmul_rn(dx, dx), __fmul_rn(dy, dy)), __fmul_rn(dz, dz)) < R2;
        }

        // ---- query 0: ordered slot scatter (r5-proven) ----
        int cnt0, gfin0;
        {
            const unsigned long long bal0 = __ballot(va0);
            const unsigned long long bal1 = __ballot(va1);
            const int c0   = (int)__popcll(bal0);
            cnt0 = c0 + (int)__popcll(bal1);
            const int pos0 = (int)__popcll(bal0 & below);
            const int pos1 = c0 + (int)__popcll(bal1 & below);
            const int addr0 = (va0 && pos0 < NS) ? (pos0 << 2) : junk;
            const int addr1 = (va1 && pos1 < NS) ? (pos1 << 2) : junk;
            const int perm0 = __builtin_amdgcn_ds_permute(addr0, pa0);
            const int perm1 = __builtin_amdgcn_ds_permute(addr1, pa1);
            const int sel   = (lane < c0) ? perm0 : perm1;
            const int first = __shfl(sel, 0);
            const int c16   = cnt0 < NS ? cnt0 : NS;
            gfin0 = (cnt0 == 0) ? cur.boff0 : (((lane & 15) < c16) ? sel : first);
        }
        // ---- query 1 ----
        int cnt1 = 0, gfin1 = 0;
        if (has1) {
            const unsigned long long bal0 = __ballot(vb0);
            const unsigned long long bal1 = __ballot(vb1);
            const int c0   = (int)__popcll(bal0);
            cnt1 = c0 + (int)__popcll(bal1);
            const int pos0 = (int)__popcll(bal0 & below);
            const int pos1 = c0 + (int)__popcll(bal1 & below);
            const int addr0 = (vb0 && pos0 < NS) ? (pos0 << 2) : junk;
            const int addr1 = (vb1 && pos1 < NS) ? (pos1 << 2) : junk;
            const int perm0 = __builtin_amdgcn_ds_permute(addr0, pb0);
            const int perm1 = __builtin_amdgcn_ds_permute(addr1, pb1);
            const int sel   = (lane < c0) ? perm0 : perm1;
            const int first = __shfl(sel, 0);
            const int c16   = cnt1 < NS ? cnt1 : NS;
            gfin1 = (cnt1 == 0) ? cur.boff1 : (((lane & 15) < c16) ? sel : first);
        }

        // ---- grouped_xyz + empty: r5's exact passing pattern ----
        {
            const int s = lane & 15;
            const int d = lane >> 4;
            if (lane < 48) {
                const int row = __shfl(gfin0, s);
                __builtin_nontemporal_store(xyz[(size_t)row * 3 + d],
                                            out_xyz + (size_t)m0 * 48 + d * 16 + s);
            }
            if (lane == 0)
                __builtin_nontemporal_store(cnt0 == 0 ? 1.0f : 0.0f, out_empty + m0);
            if (has1) {
                if (lane < 48) {
                    const int row = __shfl(gfin1, s);
                    __builtin_nontemporal_store(xyz[(size_t)row * 3 + d],
                                                out_xyz + (size_t)m1 * 48 + d * 16 + s);
                }
                if (lane == 0)
                    __builtin_nontemporal_store(cnt1 == 0 ? 1.0f : 0.0f, out_empty + m1);
            }
        }

        // ---- grouped_features: r5's exact passing pattern ----
        const int s0lane = (lane & 3) << 2;
        const int a_r0 = __shfl(gfin0, s0lane + 0);
        const int a_r1 = __shfl(gfin0, s0lane + 1);
        const int a_r2 = __shfl(gfin0, s0lane + 2);
        const int a_r3 = __shfl(gfin0, s0lane + 3);
        const int b_r0 = __shfl(gfin1, s0lane + 0);
        const int b_r1 = __shfl(gfin1, s0lane + 1);
        const int b_r2 = __shfl(gfin1, s0lane + 2);
        const int b_r3 = __shfl(gfin1, s0lane + 3);

        float* __restrict__ of0 = out_feat + (size_t)m0 * (CF * NS);
        float* __restrict__ of1 = out_feat + (size_t)m1 * (CF * NS);
        #pragma unroll
        for (int k = 0; k < 2; ++k) {
            const int c = k * 16 + (lane >> 2);
            v4f v;
            v[0] = features[(size_t)a_r0 * CF + c];
            v[1] = features[(size_t)a_r1 * CF + c];
            v[2] = features[(size_t)a_r2 * CF + c];
            v[3] = features[(size_t)a_r3 * CF + c];
            __builtin_nontemporal_store(v, reinterpret_cast<v4f*>(of0 + k * 256 + (lane << 2)));
        }
        if (has1) {
            #pragma unroll
            for (int k = 0; k < 2; ++k) {
                const int c = k * 16 + (lane >> 2);
                v4f v;
                v[0] = features[(size_t)b_r0 * CF + c];
                v[1] = features[(size_t)b_r1 * CF + c];
                v[2] = features[(size_t)b_r2 * CF + c];
                v[3] = features[(size_t)b_r3 * CF + c];
                __builtin_nontemporal_store(v, reinterpret_cast<v4f*>(of1 + k * 256 + (lane << 2)));
            }
        }

        if (!hasnext) break;
        cur = nxt;
        pa0 = na0; pa1 = na1; pb0 = nb0; pb1 = nb1;
        slot = nslot;
    }
}

extern "C" void kernel_launch(void* const* d_in, const int* in_sizes, int n_in,
                              void* d_out, int out_size, void* d_ws, size_t ws_size,
                              hipStream_t stream) {
    const int*   new_coords    = (const int*)d_in[0];
    const float* xyz           = (const float*)d_in[1];
    const int*   xyz_batch_cnt = (const int*)d_in[2];
    const float* new_xyz       = (const float*)d_in[3];
    // d_in[4] = new_xyz_batch_cnt (unused)
    const float* features      = (const float*)d_in[5];
    const int*   v2p           = (const int*)d_in[6];

    const int M = in_sizes[0] / 4;

    float* out_feat  = (float*)d_out;                       // M*CF*NS
    float* out_xyz   = out_feat + (size_t)M * CF * NS;      // M*3*NS
    float* out_empty = out_xyz + (size_t)M * 3 * NS;        // M

    // Persistent: 2048 blocks x 4 waves = 8192 waves (32 waves/CU), each
    // grid-strides over ~3-4 query pairs with cross-iteration prefetch.
    const int npairs = (M + 1) / 2;
    const int nwaves = 8192;
    int blocks = (nwaves * 64) / 256;                       // 2048
    const int needed = (npairs + 3) / 4;                    // waves/4 rounded
    if (blocks > needed) blocks = needed;
    vqg_kernel<<<blocks, 256, 0, stream>>>(
        new_coords, xyz, xyz_batch_cnt, new_xyz, features, v2p,
        out_feat, out_xyz, out_empty, M, blocks * 4);
}

// Round 11
// 53.757 us; speedup vs baseline: 2.4332x; 2.4332x over previous
//
#include <hip/hip_runtime.h>

// VoxelQueryAndGrouping — MI355X (gfx950), round 11
// = round-5 kernel (PASSED, 53.4us; QPW=2, barrier-free, ds_permute slot
//   scatter) with ONE delta: all v2p / candidate-xyz gathers are
//   UNCONDITIONAL with clamped addresses (the reference's own formulation:
//   nbc=clip(...), pts=xyz[max(pidx,0)], mask applied afterwards).
//   Removes 16 exec-mask branch regions so the loads issue as clauses.
// Output-producing code is byte-identical to round 5. Single kernel.

constexpr int ZG = 21;
constexpr int YG = 400;
constexpr int XG = 352;
constexpr int NS = 16;   // NSAMPLE
constexpr int CF = 32;   // feature channels
constexpr float R2 = 64.0f; // RADIUS^2

typedef float v4f __attribute__((ext_vector_type(4)));

__device__ __forceinline__ int clampi(int v, int lo, int hi) {
    return v < lo ? lo : (v > hi ? hi : v);
}

__global__ __launch_bounds__(256) void vqg_kernel(
    const int*   __restrict__ new_coords,     // (M,4) [b,z,y,x]
    const float* __restrict__ xyz,            // (N,3)
    const int*   __restrict__ xyz_batch_cnt,  // (B,)
    const float* __restrict__ new_xyz,        // (M,3)
    const float* __restrict__ features,       // (N,CF)
    const int*   __restrict__ v2p,            // (B,ZG,YG,XG)
    float* __restrict__ out_feat,             // (M,CF,NS)
    float* __restrict__ out_xyz,              // (M,3,NS)
    float* __restrict__ out_empty,            // (M,)
    int M)
{
    const int lane = threadIdx.x & 63;
    const int w    = (blockIdx.x * 256 + threadIdx.x) >> 6;  // wave id
    const int m0   = w * 2;
    const int m1   = m0 + 1;
    if (m0 >= M) return;                      // wave-uniform exit
    const bool has1 = (m1 < M);

    // ---- query descriptors (wave-uniform lines) ----
    const int4 qc0 = *reinterpret_cast<const int4*>(new_coords + (size_t)m0 * 4);
    const int4 qc1 = has1 ? *reinterpret_cast<const int4*>(new_coords + (size_t)m1 * 4) : qc0;
    const float qx0 = new_xyz[m0 * 3 + 0], qy0 = new_xyz[m0 * 3 + 1], qz0 = new_xyz[m0 * 3 + 2];
    const float qx1 = has1 ? new_xyz[m1 * 3 + 0] : 0.f;
    const float qy1 = has1 ? new_xyz[m1 * 3 + 1] : 0.f;
    const float qz1 = has1 ? new_xyz[m1 * 3 + 2] : 0.f;

    int boff0 = 0, boff1 = 0;
    for (int i = 0; i < qc0.x; ++i) boff0 += xyz_batch_cnt[i];
    for (int i = 0; i < qc1.x; ++i) boff1 += xyz_batch_cnt[i];

    // ---- neighbor decode (reference order: dz slowest, dx fastest) ----
    const int n1 = 64 + lane;
    const int dz0 = lane / 25 - 2, dy0 = (lane / 5) % 5 - 2, dx0 = lane % 5 - 2;
    const int dz1 = n1 / 25 - 2,   dy1 = (n1 / 5) % 5 - 2,   dx1 = n1 % 5 - 2;
    const bool in1 = (n1 < 125);

    const int* __restrict__ gb0 = v2p + (size_t)qc0.x * (ZG * YG * XG);
    const int* __restrict__ gb1 = v2p + (size_t)qc1.x * (ZG * YG * XG);

    // ---- v2p gathers: UNCONDITIONAL, clamped coords (reference's nbc=clip) ----
    bool inb_a0, inb_a1, inb_b0, inb_b1;
    int pa0, pa1, pb0, pb1;                   // raw grid values (mask later)
    {
        const int z = qc0.y + dz0, y = qc0.z + dy0, x = qc0.w + dx0;
        inb_a0 = (unsigned)z < (unsigned)ZG && (unsigned)y < (unsigned)YG && (unsigned)x < (unsigned)XG;
        pa0 = gb0[((size_t)clampi(z,0,ZG-1) * YG + clampi(y,0,YG-1)) * XG + clampi(x,0,XG-1)];
    }
    {
        const int z = qc0.y + dz1, y = qc0.z + dy1, x = qc0.w + dx1;
        inb_a1 = in1 && (unsigned)z < (unsigned)ZG && (unsigned)y < (unsigned)YG && (unsigned)x < (unsigned)XG;
        pa1 = gb0[((size_t)clampi(z,0,ZG-1) * YG + clampi(y,0,YG-1)) * XG + clampi(x,0,XG-1)];
    }
    {
        const int z = qc1.y + dz0, y = qc1.z + dy0, x = qc1.w + dx0;
        inb_b0 = has1 && (unsigned)z < (unsigned)ZG && (unsigned)y < (unsigned)YG && (unsigned)x < (unsigned)XG;
        pb0 = gb1[((size_t)clampi(z,0,ZG-1) * YG + clampi(y,0,YG-1)) * XG + clampi(x,0,XG-1)];
    }
    {
        const int z = qc1.y + dz1, y = qc1.z + dy1, x = qc1.w + dx1;
        inb_b1 = has1 && in1 && (unsigned)z < (unsigned)ZG && (unsigned)y < (unsigned)YG && (unsigned)x < (unsigned)XG;
        pb1 = gb1[((size_t)clampi(z,0,ZG-1) * YG + clampi(y,0,YG-1)) * XG + clampi(x,0,XG-1)];
    }

    // ---- candidate gathers: UNCONDITIONAL, row = max(pidx,0) (reference) ----
    const int ra0 = pa0 > 0 ? pa0 : 0;
    const int ra1 = pa1 > 0 ? pa1 : 0;
    const int rb0 = pb0 > 0 ? pb0 : 0;
    const int rb1 = pb1 > 0 ? pb1 : 0;
    const float a0x = xyz[(size_t)ra0 * 3 + 0], a0y = xyz[(size_t)ra0 * 3 + 1], a0z = xyz[(size_t)ra0 * 3 + 2];
    const float a1x = xyz[(size_t)ra1 * 3 + 0], a1y = xyz[(size_t)ra1 * 3 + 1], a1z = xyz[(size_t)ra1 * 3 + 2];
    const float b0x = xyz[(size_t)rb0 * 3 + 0], b0y = xyz[(size_t)rb0 * 3 + 1], b0z = xyz[(size_t)rb0 * 3 + 2];
    const float b1x = xyz[(size_t)rb1 * 3 + 0], b1y = xyz[(size_t)rb1 * 3 + 1], b1z = xyz[(size_t)rb1 * 3 + 2];

    // ---- distances on all lanes; validity masked afterwards (reference) ----
    bool va0, va1, vb0, vb1;
    {
        const float dx = a0x - qx0, dy = a0y - qy0, dz = a0z - qz0;
        const float d2 = __fadd_rn(__fadd_rn(__fmul_rn(dx, dx), __fmul_rn(dy, dy)), __fmul_rn(dz, dz));
        va0 = inb_a0 && (pa0 >= 0) && (d2 < R2);
    }
    {
        const float dx = a1x - qx0, dy = a1y - qy0, dz = a1z - qz0;
        const float d2 = __fadd_rn(__fadd_rn(__fmul_rn(dx, dx), __fmul_rn(dy, dy)), __fmul_rn(dz, dz));
        va1 = inb_a1 && (pa1 >= 0) && (d2 < R2);
    }
    {
        const float dx = b0x - qx1, dy = b0y - qy1, dz = b0z - qz1;
        const float d2 = __fadd_rn(__fadd_rn(__fmul_rn(dx, dx), __fmul_rn(dy, dy)), __fmul_rn(dz, dz));
        vb0 = inb_b0 && (pb0 >= 0) && (d2 < R2);
    }
    {
        const float dx = b1x - qx1, dy = b1y - qy1, dz = b1z - qz1;
        const float d2 = __fadd_rn(__fadd_rn(__fmul_rn(dx, dx), __fmul_rn(dy, dy)), __fmul_rn(dz, dz));
        vb1 = inb_b1 && (pb1 >= 0) && (d2 < R2);
    }

    const unsigned long long below = (1ull << lane) - 1ull;
    const int junk = (16 + (lane & 31)) << 2;

    // ---- query 0: ordered slot scatter (r5-proven) ----
    int cnt0, gfin0;
    {
        const unsigned long long bal0 = __ballot(va0);
        const unsigned long long bal1 = __ballot(va1);
        const int c0   = (int)__popcll(bal0);
        cnt0 = c0 + (int)__popcll(bal1);
        const int pos0 = (int)__popcll(bal0 & below);
        const int pos1 = c0 + (int)__popcll(bal1 & below);
        const int addr0 = (va0 && pos0 < NS) ? (pos0 << 2) : junk;
        const int addr1 = (va1 && pos1 < NS) ? (pos1 << 2) : junk;
        const int perm0 = __builtin_amdgcn_ds_permute(addr0, pa0);
        const int perm1 = __builtin_amdgcn_ds_permute(addr1, pa1);
        const int sel   = (lane < c0) ? perm0 : perm1;
        const int first = __shfl(sel, 0);
        const int c16   = cnt0 < NS ? cnt0 : NS;
        gfin0 = (cnt0 == 0) ? boff0 : (((lane & 15) < c16) ? sel : first);
    }
    // ---- query 1 ----
    int cnt1 = 0, gfin1 = 0;
    if (has1) {
        const unsigned long long bal0 = __ballot(vb0);
        const unsigned long long bal1 = __ballot(vb1);
        const int c0   = (int)__popcll(bal0);
        cnt1 = c0 + (int)__popcll(bal1);
        const int pos0 = (int)__popcll(bal0 & below);
        const int pos1 = c0 + (int)__popcll(bal1 & below);
        const int addr0 = (vb0 && pos0 < NS) ? (pos0 << 2) : junk;
        const int addr1 = (vb1 && pos1 < NS) ? (pos1 << 2) : junk;
        const int perm0 = __builtin_amdgcn_ds_permute(addr0, pb0);
        const int perm1 = __builtin_amdgcn_ds_permute(addr1, pb1);
        const int sel   = (lane < c0) ? perm0 : perm1;
        const int first = __shfl(sel, 0);
        const int c16   = cnt1 < NS ? cnt1 : NS;
        gfin1 = (cnt1 == 0) ? boff1 : (((lane & 15) < c16) ? sel : first);
    }

    // ---- grouped_xyz + empty: r5's exact passing pattern ----
    {
        const int s = lane & 15;
        const int d = lane >> 4;
        if (lane < 48) {
            const int row = __shfl(gfin0, s);
            __builtin_nontemporal_store(xyz[(size_t)row * 3 + d],
                                        out_xyz + (size_t)m0 * 48 + d * 16 + s);
        }
        if (lane == 0)
            __builtin_nontemporal_store(cnt0 == 0 ? 1.0f : 0.0f, out_empty + m0);
        if (has1) {
            if (lane < 48) {
                const int row = __shfl(gfin1, s);
                __builtin_nontemporal_store(xyz[(size_t)row * 3 + d],
                                            out_xyz + (size_t)m1 * 48 + d * 16 + s);
            }
            if (lane == 0)
                __builtin_nontemporal_store(cnt1 == 0 ? 1.0f : 0.0f, out_empty + m1);
        }
    }

    // ---- grouped_features: r5's exact passing pattern ----
    const int s0lane = (lane & 3) << 2;
    const int a_r0 = __shfl(gfin0, s0lane + 0);
    const int a_r1 = __shfl(gfin0, s0lane + 1);
    const int a_r2 = __shfl(gfin0, s0lane + 2);
    const int a_r3 = __shfl(gfin0, s0lane + 3);
    const int b_r0 = __shfl(gfin1, s0lane + 0);
    const int b_r1 = __shfl(gfin1, s0lane + 1);
    const int b_r2 = __shfl(gfin1, s0lane + 2);
    const int b_r3 = __shfl(gfin1, s0lane + 3);

    float* __restrict__ of0 = out_feat + (size_t)m0 * (CF * NS);
    float* __restrict__ of1 = out_feat + (size_t)m1 * (CF * NS);
    #pragma unroll
    for (int k = 0; k < 2; ++k) {
        const int c = k * 16 + (lane >> 2);
        v4f v;
        v[0] = features[(size_t)a_r0 * CF + c];
        v[1] = features[(size_t)a_r1 * CF + c];
        v[2] = features[(size_t)a_r2 * CF + c];
        v[3] = features[(size_t)a_r3 * CF + c];
        __builtin_nontemporal_store(v, reinterpret_cast<v4f*>(of0 + k * 256 + (lane << 2)));
    }
    if (has1) {
        #pragma unroll
        for (int k = 0; k < 2; ++k) {
            const int c = k * 16 + (lane >> 2);
            v4f v;
            v[0] = features[(size_t)b_r0 * CF + c];
            v[1] = features[(size_t)b_r1 * CF + c];
            v[2] = features[(size_t)b_r2 * CF + c];
            v[3] = features[(size_t)b_r3 * CF + c];
            __builtin_nontemporal_store(v, reinterpret_cast<v4f*>(of1 + k * 256 + (lane << 2)));
        }
    }
}

extern "C" void kernel_launch(void* const* d_in, const int* in_sizes, int n_in,
                              void* d_out, int out_size, void* d_ws, size_t ws_size,
                              hipStream_t stream) {
    const int*   new_coords    = (const int*)d_in[0];
    const float* xyz           = (const float*)d_in[1];
    const int*   xyz_batch_cnt = (const int*)d_in[2];
    const float* new_xyz       = (const float*)d_in[3];
    // d_in[4] = new_xyz_batch_cnt (unused)
    const float* features      = (const float*)d_in[5];
    const int*   v2p           = (const int*)d_in[6];

    const int M = in_sizes[0] / 4;

    float* out_feat  = (float*)d_out;                       // M*CF*NS
    float* out_xyz   = out_feat + (size_t)M * CF * NS;      // M*3*NS
    float* out_empty = out_xyz + (size_t)M * 3 * NS;        // M

    const int waves  = (M + 1) / 2;           // 2 queries per wave
    const int blocks = (waves + 3) / 4;       // 4 waves per block
    vqg_kernel<<<blocks, 256, 0, stream>>>(
        new_coords, xyz, xyz_batch_cnt, new_xyz, features, v2p,
        out_feat, out_xyz, out_empty, M);
}